// Round 2
// baseline (1177.050 us; speedup 1.0000x reference)
//
#include <hip/hip_runtime.h>

// Problem constants: B=2, L=2048, D=2048, H=16, DH=128, M=B*L=4096
typedef unsigned short u16;
typedef __bf16 bfrag __attribute__((ext_vector_type(8)));   // 8 bf16 = 4 VGPRs (MFMA A/B frag)
typedef float f32x4 __attribute__((ext_vector_type(4)));    // MFMA C/D frag

#define MFMA16 __builtin_amdgcn_mfma_f32_16x16x32_bf16

__device__ __forceinline__ u16 f2bf(float f) {
  unsigned u = __builtin_bit_cast(unsigned, f);
  u += 0x7fffu + ((u >> 16) & 1u);          // RNE
  return (u16)(u >> 16);
}
__device__ __forceinline__ float bf2f(u16 s) {
  return __builtin_bit_cast(float, (unsigned)s << 16);
}
__device__ __forceinline__ void splitf(float x, u16 &h, u16 &l) {
  h = f2bf(x);
  l = f2bf(x - bf2f(h));                    // exact residual, then RNE
}

// ---------------------------------------------------------------------------
// Pre-split a fp32 weight matrix into bf16 hi/lo (removes the 32x-redundant
// per-tile splitf inside the Q/K GEMMs).
// ---------------------------------------------------------------------------
__global__ void presplit_w(const float* __restrict__ W, u16* __restrict__ hi,
                           u16* __restrict__ lo)
{
  int i = blockIdx.x * 256 + threadIdx.x;   // one float4 per thread
  float4 x = *(const float4*)(W + (size_t)i * 4);
  ushort4 h, l;
  splitf(x.x, h.x, l.x); splitf(x.y, h.y, l.y);
  splitf(x.z, h.z, l.z); splitf(x.w, h.w, l.w);
  *(ushort4*)(hi + (size_t)i * 4) = h;
  *(ushort4*)(lo + (size_t)i * 4) = l;
}

// ---------------------------------------------------------------------------
// Split GEMM for Q/K projections: C = A[4096][2048] @ W[2048][2048]^T + bias
// A fp32 (split in-kernel), W pre-split bf16 hi/lo. 3-MFMA hi/lo products.
// EMIT 0: scale by sqrt(128), split, store bf16 hi/lo [B,H,L,DH]  (Q)
// EMIT 1: split, store bf16 hi/lo [B,H,L,DH]                      (K)
// ---------------------------------------------------------------------------
template<int EMIT>
__global__ __launch_bounds__(256, 2)
void gemm_qk(const float* __restrict__ A, const u16* __restrict__ Wh_g,
             const u16* __restrict__ Wl_g, const float* __restrict__ bias,
             u16* __restrict__ ohi, u16* __restrict__ olo)
{
  __shared__ u16 Ahi[128][40];
  __shared__ u16 Alo[128][40];
  __shared__ u16 Whs[128][40];
  __shared__ u16 Wls[128][40];

  const int tid = threadIdx.x, wave = tid >> 6, lane = tid & 63;
  const int quad = lane >> 4, l16 = lane & 15;
  const int bm = blockIdx.y * 128, bn = blockIdx.x * 128;
  const int wm = (wave >> 1) * 64, wn = (wave & 1) * 64;

  f32x4 acc[4][4] = {};

  for (int k0 = 0; k0 < 2048; k0 += 32) {
    __syncthreads();
    // A: 128x32 fp32 -> hi/lo bf16 (4 float4/thread)
#pragma unroll
    for (int it = 0; it < 4; ++it) {
      int idx = tid + it * 256;
      int row = idx >> 3, c4 = (idx & 7) << 2;
      float4 av = *(const float4*)(A + (size_t)(bm + row) * 2048 + k0 + c4);
      ushort4 h, l;
      splitf(av.x, h.x, l.x); splitf(av.y, h.y, l.y);
      splitf(av.z, h.z, l.z); splitf(av.w, h.w, l.w);
      *(ushort4*)&Ahi[row][c4] = h;
      *(ushort4*)&Alo[row][c4] = l;
    }
    // W: 128x32 bf16 hi/lo straight copies (2x 16B per buffer per thread)
#pragma unroll
    for (int it = 0; it < 2; ++it) {
      int idx = tid + it * 256;
      int row = idx >> 2, c8 = (idx & 3) << 3;
      *(uint4*)&Whs[row][c8] =
          *(const uint4*)(Wh_g + (size_t)(bn + row) * 2048 + k0 + c8);
      *(uint4*)&Wls[row][c8] =
          *(const uint4*)(Wl_g + (size_t)(bn + row) * 2048 + k0 + c8);
    }
    __syncthreads();

    bfrag af[4], al[4], bh[4], bl[4];
#pragma unroll
    for (int i = 0; i < 4; ++i) {
      af[i] = *(const bfrag*)&Ahi[wm + i * 16 + l16][quad * 8];
      al[i] = *(const bfrag*)&Alo[wm + i * 16 + l16][quad * 8];
      bh[i] = *(const bfrag*)&Whs[wn + i * 16 + l16][quad * 8];
      bl[i] = *(const bfrag*)&Wls[wn + i * 16 + l16][quad * 8];
    }
#pragma unroll
    for (int mi = 0; mi < 4; ++mi)
#pragma unroll
      for (int ni = 0; ni < 4; ++ni) {
        acc[mi][ni] = MFMA16(af[mi], bh[ni], acc[mi][ni], 0, 0, 0);
        acc[mi][ni] = MFMA16(af[mi], bl[ni], acc[mi][ni], 0, 0, 0);
        acc[mi][ni] = MFMA16(al[mi], bh[ni], acc[mi][ni], 0, 0, 0);
      }
  }

  const float SCALE = 11.31370849898476f;   // sqrt(128) — faithful source bug
#pragma unroll
  for (int ni = 0; ni < 4; ++ni) {
    int n_g = bn + wn + ni * 16 + l16;
    float bv = bias[n_g];
#pragma unroll
    for (int mi = 0; mi < 4; ++mi)
#pragma unroll
      for (int r = 0; r < 4; ++r) {
        int m_g = bm + wm + mi * 16 + quad * 4 + r;
        float v = acc[mi][ni][r] + bv;
        if constexpr (EMIT == 0) v *= SCALE;
        u16 h, l; splitf(v, h, l);
        int b = m_g >> 11, ll = m_g & 2047, hh = n_g >> 7, dh = n_g & 127;
        size_t off = (((size_t)(b * 16 + hh)) * 2048 + ll) * 128 + dh;
        ohi[off] = h; olo[off] = l;
      }
  }
}

// ---------------------------------------------------------------------------
// Plain bf16 GEMM for V projection and output projection.
// AMODE: 0 = A fp32 global, 1 = A bf16 global
// OUTM : 1 = bf16 to [B,H,DH,L] (transposed V)   2 = fp32 [M][N]
// ---------------------------------------------------------------------------
template<int AMODE, int OUTM>
__global__ __launch_bounds__(256, 2)
void gemm_k(const void* __restrict__ Ap, const float* __restrict__ W,
            const float* __restrict__ bias, void* __restrict__ outp)
{
  __shared__ u16 Ahi[128][40];
  __shared__ u16 Whi[128][40];

  const int tid = threadIdx.x, wave = tid >> 6, lane = tid & 63;
  const int quad = lane >> 4, l16 = lane & 15;
  const int bm = blockIdx.y * 128, bn = blockIdx.x * 128;
  const int wm = (wave >> 1) * 64, wn = (wave & 1) * 64;

  f32x4 acc[4][4] = {};

  for (int k0 = 0; k0 < 2048; k0 += 32) {
    __syncthreads();
#pragma unroll
    for (int it = 0; it < 4; ++it) {
      int idx = tid + it * 256;
      int row = idx >> 3, c4 = (idx & 7) << 2;
      {
        float4 wv = *(const float4*)(W + (size_t)(bn + row) * 2048 + k0 + c4);
        ushort4 h;
        h.x = f2bf(wv.x); h.y = f2bf(wv.y); h.z = f2bf(wv.z); h.w = f2bf(wv.w);
        *(ushort4*)&Whi[row][c4] = h;
      }
      if constexpr (AMODE == 0) {
        const float* A = (const float*)Ap;
        float4 av = *(const float4*)(A + (size_t)(bm + row) * 2048 + k0 + c4);
        ushort4 h;
        h.x = f2bf(av.x); h.y = f2bf(av.y); h.z = f2bf(av.z); h.w = f2bf(av.w);
        *(ushort4*)&Ahi[row][c4] = h;
      } else {
        const u16* A = (const u16*)Ap;
        *(ushort4*)&Ahi[row][c4] =
            *(const ushort4*)(A + (size_t)(bm + row) * 2048 + k0 + c4);
      }
    }
    __syncthreads();

    bfrag af[4], bfv[4];
#pragma unroll
    for (int i = 0; i < 4; ++i) {
      af[i] = *(const bfrag*)&Ahi[wm + i * 16 + l16][quad * 8];
      bfv[i] = *(const bfrag*)&Whi[wn + i * 16 + l16][quad * 8];
    }
#pragma unroll
    for (int mi = 0; mi < 4; ++mi)
#pragma unroll
      for (int ni = 0; ni < 4; ++ni)
        acc[mi][ni] = MFMA16(af[mi], bfv[ni], acc[mi][ni], 0, 0, 0);
  }

#pragma unroll
  for (int ni = 0; ni < 4; ++ni) {
    int n_g = bn + wn + ni * 16 + l16;
    float bv = bias[n_g];
#pragma unroll
    for (int mi = 0; mi < 4; ++mi)
#pragma unroll
      for (int r = 0; r < 4; ++r) {
        int m_g = bm + wm + mi * 16 + quad * 4 + r;
        float v = acc[mi][ni][r] + bv;
        if constexpr (OUTM == 1) {        // bf16 [B,H,DH,L] (transposed V)
          int b = m_g >> 11, l = m_g & 2047, h = n_g >> 7, dh = n_g & 127;
          ((u16*)outp)[(((size_t)(b * 16 + h)) * 128 + dh) * 2048 + l] = f2bf(v);
        } else {                          // fp32 [M][N] == [B,L,D]
          ((float*)outp)[(size_t)m_g * 2048 + n_g] = v;
        }
      }
  }
}

// ---------------------------------------------------------------------------
// Flash attention (causal). Q pre-scaled by sqrt(128) and pre-split; K
// pre-split; V pre-transposed. All-bf16 staging with register double-buffer
// prefetch of the next KV tile. 2 barriers per iteration.
// ---------------------------------------------------------------------------
__global__ __launch_bounds__(256, 2)
void attn_k(const u16* __restrict__ qhi_g, const u16* __restrict__ qlo_g,
            const u16* __restrict__ khi_g, const u16* __restrict__ klo_g,
            const u16* __restrict__ vT, u16* __restrict__ Ow)
{
  __shared__ u16 Khi[64][136];   // 128 + 8 pad (272B rows: 16B-aligned, 2-way alias free)
  __shared__ u16 Klo[64][136];
  __shared__ u16 VT[128][72];    // [dh][kv], 64 + 8 pad
  __shared__ u16 Pm[4][32][72];  // per-wave P tile: C-layout -> A-layout round trip

  const int tid = threadIdx.x, wave = tid >> 6, lane = tid & 63;
  const int quad = lane >> 4, l16 = lane & 15;
  const int qtile = blockIdx.x, bh = blockIdx.y;
  const u16* Qhb = qhi_g + (size_t)bh * 2048 * 128;
  const u16* Qlb = qlo_g + (size_t)bh * 2048 * 128;
  const u16* Khb = khi_g + (size_t)bh * 2048 * 128;
  const u16* Klb = klo_g + (size_t)bh * 2048 * 128;
  const u16* Vb  = vT    + (size_t)bh * 128 * 2048;
  const int qrow0 = qtile * 128 + wave * 32;

  // Q fragments (hi/lo), direct bf16 loads — A-layout already
  bfrag qhf[2][4], qlf[2][4];
#pragma unroll
  for (int t = 0; t < 2; ++t)
#pragma unroll
    for (int f = 0; f < 4; ++f) {
      size_t off = (size_t)(qrow0 + t * 16 + l16) * 128 + f * 32 + quad * 8;
      qhf[t][f] = *(const bfrag*)(Qhb + off);
      qlf[t][f] = *(const bfrag*)(Qlb + off);
    }

  float mprev[2][4], lsum[2][4];
  f32x4 o[2][8] = {};
#pragma unroll
  for (int t = 0; t < 2; ++t)
#pragma unroll
    for (int r = 0; r < 4; ++r) { mprev[t][r] = -3e38f; lsum[t][r] = 0.f; }

  // prefetch registers for the next KV tile (K hi/lo: 64x128, V^T: 128x64)
  uint4 rkh[4], rkl[4], rv[4];
  auto load_tile = [&](int kv0) {
#pragma unroll
    for (int it = 0; it < 4; ++it) {
      int idx = tid + it * 256;
      rkh[it] = *(const uint4*)(Khb + (size_t)(kv0 + (idx >> 4)) * 128 + ((idx & 15) << 3));
      rkl[it] = *(const uint4*)(Klb + (size_t)(kv0 + (idx >> 4)) * 128 + ((idx & 15) << 3));
      rv[it]  = *(const uint4*)(Vb  + (size_t)(idx >> 3) * 2048 + kv0 + ((idx & 7) << 3));
    }
  };

  const int nkv = 2 * (qtile + 1);
  load_tile(0);
  for (int kt = 0; kt < nkv; ++kt) {
    const int kv0 = kt * 64;
    __syncthreads();                        // all waves done reading previous LDS
#pragma unroll
    for (int it = 0; it < 4; ++it) {
      int idx = tid + it * 256;
      *(uint4*)&Khi[idx >> 4][(idx & 15) << 3] = rkh[it];
      *(uint4*)&Klo[idx >> 4][(idx & 15) << 3] = rkl[it];
      *(uint4*)&VT [idx >> 3][(idx & 7) << 3]  = rv[it];
    }
    if (kt + 1 < nkv) load_tile((kt + 1) * 64);   // in flight during compute
    __syncthreads();                        // LDS tile visible

    // S = Q K^T (split: hh + hl + lh), pre-scaled
    f32x4 s[2][4] = {};
#pragma unroll
    for (int f = 0; f < 4; ++f)
#pragma unroll
      for (int c = 0; c < 4; ++c) {
        bfrag kf = *(const bfrag*)&Khi[c * 16 + l16][f * 32 + quad * 8];
        bfrag kl = *(const bfrag*)&Klo[c * 16 + l16][f * 32 + quad * 8];
#pragma unroll
        for (int t = 0; t < 2; ++t) {
          s[t][c] = MFMA16(qhf[t][f], kf, s[t][c], 0, 0, 0);
          s[t][c] = MFMA16(qhf[t][f], kl, s[t][c], 0, 0, 0);
          s[t][c] = MFMA16(qlf[t][f], kf, s[t][c], 0, 0, 0);
        }
      }

    // online softmax; rows of a 16-tile live across 16 lanes of a quad
#pragma unroll
    for (int t = 0; t < 2; ++t)
#pragma unroll
      for (int r = 0; r < 4; ++r) {
        const int rg = qrow0 + t * 16 + quad * 4 + r;
        float sv[4];
#pragma unroll
        for (int c = 0; c < 4; ++c) {
          int cg = kv0 + c * 16 + l16;
          sv[c] = (cg <= rg) ? s[t][c][r] : -1e7f;
        }
        float mx = fmaxf(fmaxf(sv[0], sv[1]), fmaxf(sv[2], sv[3]));
#pragma unroll
        for (int off = 1; off < 16; off <<= 1) mx = fmaxf(mx, __shfl_xor(mx, off));
        float mnew = fmaxf(mprev[t][r], mx);
        float al = __expf(mprev[t][r] - mnew);
        float ps = 0.f;
#pragma unroll
        for (int c = 0; c < 4; ++c) { sv[c] = __expf(sv[c] - mnew); ps += sv[c]; }
#pragma unroll
        for (int off = 1; off < 16; off <<= 1) ps += __shfl_xor(ps, off);
        lsum[t][r] = lsum[t][r] * al + ps;
        mprev[t][r] = mnew;
#pragma unroll
        for (int d = 0; d < 8; ++d) o[t][d][r] *= al;
#pragma unroll
        for (int c = 0; c < 4; ++c)
          Pm[wave][t * 16 + quad * 4 + r][c * 16 + l16] = f2bf(sv[c]);
      }
    // no barrier: Pm is per-wave, DS pipe is in-order within a wave

    // O += P @ V
#pragma unroll
    for (int k2 = 0; k2 < 2; ++k2) {
      bfrag pf0 = *(const bfrag*)&Pm[wave][l16][k2 * 32 + quad * 8];
      bfrag pf1 = *(const bfrag*)&Pm[wave][16 + l16][k2 * 32 + quad * 8];
#pragma unroll
      for (int d = 0; d < 8; ++d) {
        bfrag vf = *(const bfrag*)&VT[d * 16 + l16][k2 * 32 + quad * 8];
        o[0][d] = MFMA16(pf0, vf, o[0][d], 0, 0, 0);
        o[1][d] = MFMA16(pf1, vf, o[1][d], 0, 0, 0);
      }
    }
  }

  // epilogue: normalize, store bf16 to O[B,L,D]
  const int b = bh >> 4, h = bh & 15;
#pragma unroll
  for (int t = 0; t < 2; ++t)
#pragma unroll
    for (int r = 0; r < 4; ++r) {
      int rg = qrow0 + t * 16 + quad * 4 + r;
      float inv = 1.f / lsum[t][r];
#pragma unroll
      for (int d = 0; d < 8; ++d)
        Ow[((size_t)(b * 2048 + rg)) * 2048 + h * 128 + d * 16 + l16] =
            f2bf(o[t][d][r] * inv);
    }
}

// ---------------------------------------------------------------------------
extern "C" void kernel_launch(void* const* d_in, const int* in_sizes, int n_in,
                              void* d_out, int out_size, void* d_ws, size_t ws_size,
                              hipStream_t stream) {
  const float* q  = (const float*)d_in[0];
  const float* k  = (const float*)d_in[1];
  const float* v  = (const float*)d_in[2];
  const float* Wq = (const float*)d_in[3];
  const float* bq = (const float*)d_in[4];
  const float* Wk = (const float*)d_in[5];
  const float* bk = (const float*)d_in[6];
  const float* Wv = (const float*)d_in[7];
  const float* bv = (const float*)d_in[8];
  const float* Wo = (const float*)d_in[9];
  const float* bo = (const float*)d_in[10];

  // Workspace (u16 units), 100.7 MB total — proven budget from round 1:
  //   qHi qLo kHi kLo : 4 x 16.78 MB persistent (pre-split projections)
  //   T1 (16.78 MB)   : WqHi|WqLo during gemmQ, then vT
  //   T2 (16.78 MB)   : WkHi|WkLo during gemmK, then Ow
  u16* ws   = (u16*)d_ws;
  u16* qHi  = ws;
  u16* qLo  = ws + 8388608u;
  u16* kHi  = ws + 16777216u;
  u16* kLo  = ws + 25165824u;
  u16* T1   = ws + 33554432u;     // vT region
  u16* T2   = ws + 41943040u;     // Ow region
  u16* WqHi = T1, *WqLo = T1 + 4194304u;
  u16* WkHi = T2, *WkLo = T2 + 4194304u;
  u16* vT   = T1;
  u16* Ow   = T2;

  dim3 blk(256);
  dim3 gg(16, 32);   // N/128, M/128
  presplit_w<<<4096, blk, 0, stream>>>(Wq, WqHi, WqLo);
  presplit_w<<<4096, blk, 0, stream>>>(Wk, WkHi, WkLo);
  gemm_qk<0><<<gg, blk, 0, stream>>>(q, WqHi, WqLo, bq, qHi, qLo);
  gemm_qk<1><<<gg, blk, 0, stream>>>(k, WkHi, WkLo, bk, kHi, kLo);
  gemm_k<0, 1><<<gg, blk, 0, stream>>>(v, Wv, bv, vT);     // overwrites Wq split (done)
  attn_k<<<dim3(16, 32), blk, 0, stream>>>(qHi, qLo, kHi, kLo, vT, Ow); // overwrites Wk split (done)
  gemm_k<1, 2><<<gg, blk, 0, stream>>>(Ow, Wo, bo, d_out);
}

// Round 3
// 737.505 us; speedup vs baseline: 1.5960x; 1.5960x over previous
//
#include <hip/hip_runtime.h>

// Problem: B=2, L=2048, D=2048, H=16, DH=128, M=B*L=4096
typedef unsigned short u16;
typedef _Float16 hfrag __attribute__((ext_vector_type(8)));  // 8 fp16 = 4 VGPRs
typedef float f32x4 __attribute__((ext_vector_type(4)));     // MFMA C/D frag

#define MFMA16F __builtin_amdgcn_mfma_f32_16x16x32_f16

__device__ __forceinline__ u16 f2h(float f) {
  return __builtin_bit_cast(u16, (_Float16)f);
}
__device__ __forceinline__ void splith(float x, u16 &h, u16 &l) {
  _Float16 hh = (_Float16)x;                 // RNE
  _Float16 ll = (_Float16)(x - (float)hh);   // residual, ~2^-11 rel
  h = __builtin_bit_cast(u16, hh);
  l = __builtin_bit_cast(u16, ll);
}

// async global->LDS, 16B per lane. LDS dest = wave-uniform base + lane*16.
__device__ __forceinline__ void gl2lds16(const void* g, void* l) {
  __builtin_amdgcn_global_load_lds(
      (const __attribute__((address_space(1))) unsigned int*)g,
      (__attribute__((address_space(3))) unsigned int*)l, 16, 0, 0);
}

// ---------------------------------------------------------------------------
// Pre-split fp32 matrix -> fp16 hi/lo planes (one float4 per thread).
// ---------------------------------------------------------------------------
__global__ void presplit_h(const float* __restrict__ W, u16* __restrict__ hi,
                           u16* __restrict__ lo)
{
  size_t i = ((size_t)blockIdx.x * 256 + threadIdx.x) * 4;
  float4 x = *(const float4*)(W + i);
  ushort4 h, l;
  splith(x.x, h.x, l.x); splith(x.y, h.y, l.y);
  splith(x.z, h.z, l.z); splith(x.w, h.w, l.w);
  *(ushort4*)(hi + i) = h;
  *(ushort4*)(lo + i) = l;
}

// ---------------------------------------------------------------------------
// Split GEMM (Q/K proj): C[4096][2048] = A @ W^T + bias, 3-product fp16 hi/lo.
// A fp32 (split in-kernel, padded LDS); W pre-split fp16, global_load_lds
// into unpadded LDS (m97 pattern). EMIT 0: scale by sqrt(128) (Q). Output:
// fp16 hi/lo planes [B,H,L,DH].
// ---------------------------------------------------------------------------
template<int EMIT>
__global__ __launch_bounds__(256, 2)
void gemm_qk(const float* __restrict__ A, const u16* __restrict__ Wh_g,
             const u16* __restrict__ Wl_g, const float* __restrict__ bias,
             u16* __restrict__ ohi, u16* __restrict__ olo)
{
  __shared__ u16 Ahi[128][40];    // padded (80B rows, 16B-aligned)
  __shared__ u16 Alo[128][40];
  __shared__ u16 Whs[128 * 32];   // unpadded (global_load_lds dest)
  __shared__ u16 Wls[128 * 32];

  const int tid = threadIdx.x, wave = tid >> 6, lane = tid & 63;
  const int quad = lane >> 4, l16 = lane & 15;
  const int bm = blockIdx.y * 128, bn = blockIdx.x * 128;
  const int wm = (wave >> 1) * 64, wn = (wave & 1) * 64;
  const int rl = lane >> 2, cb = lane & 3;   // W staging: 16 rows x 4 blocks

  f32x4 acc[4][4] = {};

  for (int k0 = 0; k0 < 2048; k0 += 32) {
    __syncthreads();
    // async W hi/lo (8KB each): 2 issues/wave/plane
#pragma unroll
    for (int i = 0; i < 2; ++i) {
      int r0 = wave * 32 + i * 16;
      size_t goff = (size_t)(bn + r0 + rl) * 2048 + k0 + cb * 8;
      gl2lds16(Wh_g + goff, &Whs[r0 * 32]);
      gl2lds16(Wl_g + goff, &Wls[r0 * 32]);
    }
    // A: 128x32 fp32 -> fp16 hi/lo (VGPR path, overlaps the async loads)
#pragma unroll
    for (int it = 0; it < 4; ++it) {
      int idx = tid + it * 256;
      int row = idx >> 3, c4 = (idx & 7) << 2;
      float4 av = *(const float4*)(A + (size_t)(bm + row) * 2048 + k0 + c4);
      ushort4 h, l;
      splith(av.x, h.x, l.x); splith(av.y, h.y, l.y);
      splith(av.z, h.z, l.z); splith(av.w, h.w, l.w);
      *(ushort4*)&Ahi[row][c4] = h;
      *(ushort4*)&Alo[row][c4] = l;
    }
    __syncthreads();

    hfrag ah[4], al_[4], wh[4], wl[4];
#pragma unroll
    for (int i = 0; i < 4; ++i) {
      ah[i]  = *(const hfrag*)&Ahi[wm + i * 16 + l16][quad * 8];
      al_[i] = *(const hfrag*)&Alo[wm + i * 16 + l16][quad * 8];
      wh[i]  = *(const hfrag*)&Whs[(wn + i * 16 + l16) * 32 + quad * 8];
      wl[i]  = *(const hfrag*)&Wls[(wn + i * 16 + l16) * 32 + quad * 8];
    }
#pragma unroll
    for (int mi = 0; mi < 4; ++mi)
#pragma unroll
      for (int ni = 0; ni < 4; ++ni) {
        acc[mi][ni] = MFMA16F(ah[mi],  wh[ni], acc[mi][ni], 0, 0, 0);
        acc[mi][ni] = MFMA16F(al_[mi], wh[ni], acc[mi][ni], 0, 0, 0);
        acc[mi][ni] = MFMA16F(ah[mi],  wl[ni], acc[mi][ni], 0, 0, 0);
      }
  }

  const float SCALE = 11.31370849898476f;   // sqrt(128) — faithful source bug
#pragma unroll
  for (int ni = 0; ni < 4; ++ni) {
    int n_g = bn + wn + ni * 16 + l16;
    float bv = bias[n_g];
#pragma unroll
    for (int mi = 0; mi < 4; ++mi)
#pragma unroll
      for (int r = 0; r < 4; ++r) {
        int m_g = bm + wm + mi * 16 + quad * 4 + r;
        float v = acc[mi][ni][r] + bv;
        if constexpr (EMIT == 0) v *= SCALE;
        u16 h, l; splith(v, h, l);
        int b = m_g >> 11, ll = m_g & 2047, hh = n_g >> 7, dh = n_g & 127;
        size_t off = (((size_t)(b * 16 + hh)) * 2048 + ll) * 128 + dh;
        ohi[off] = h; olo[off] = l;
      }
  }
}

// ---------------------------------------------------------------------------
// Plain fp16 GEMM.
// AMODE 0: A fp32 (cvt in-kernel, padded LDS). AMODE 1: A fp16 global, staged
//          via global_load_lds (unpadded).  W always fp32, cvt in-kernel.
// OUTM 1: V-proj -> fp16 [B,H,DH,L]; computed TRANSPOSED (W rows as MFMA
//         A-operand) so stores are 32B-contiguous.  OUTM 2: fp32 [M][N].
// ---------------------------------------------------------------------------
template<int AMODE, int OUTM>
__global__ __launch_bounds__(256, 2)
void gemm_pl(const void* __restrict__ Ap, const float* __restrict__ W,
             const float* __restrict__ bias, void* __restrict__ outp)
{
  __shared__ u16 As[128 * 40];    // padded when AMODE0; stride 32 when AMODE1
  __shared__ u16 Ws[128][40];

  const int tid = threadIdx.x, wave = tid >> 6, lane = tid & 63;
  const int quad = lane >> 4, l16 = lane & 15;
  const int bm = blockIdx.y * 128, bn = blockIdx.x * 128;
  const int wm = (wave >> 1) * 64, wn = (wave & 1) * 64;
  const int rl = lane >> 2, cb = lane & 3;
  constexpr int ASTRIDE = (AMODE == 1) ? 32 : 40;

  f32x4 acc[4][4] = {};

  for (int k0 = 0; k0 < 2048; k0 += 32) {
    __syncthreads();
    if constexpr (AMODE == 1) {
      const u16* Ah = (const u16*)Ap;
#pragma unroll
      for (int i = 0; i < 2; ++i) {
        int r0 = wave * 32 + i * 16;
        gl2lds16(Ah + (size_t)(bm + r0 + rl) * 2048 + k0 + cb * 8,
                 &As[r0 * 32]);
      }
    }
#pragma unroll
    for (int it = 0; it < 4; ++it) {
      int idx = tid + it * 256;
      int row = idx >> 3, c4 = (idx & 7) << 2;
      float4 wv = *(const float4*)(W + (size_t)(bn + row) * 2048 + k0 + c4);
      ushort4 h;
      h.x = f2h(wv.x); h.y = f2h(wv.y); h.z = f2h(wv.z); h.w = f2h(wv.w);
      *(ushort4*)&Ws[row][c4] = h;
      if constexpr (AMODE == 0) {
        const float* A = (const float*)Ap;
        float4 av = *(const float4*)(A + (size_t)(bm + row) * 2048 + k0 + c4);
        ushort4 ha;
        ha.x = f2h(av.x); ha.y = f2h(av.y); ha.z = f2h(av.z); ha.w = f2h(av.w);
        *(ushort4*)&As[row * 40 + c4] = ha;
      }
    }
    __syncthreads();

    hfrag af[4], wf[4];
#pragma unroll
    for (int i = 0; i < 4; ++i) {
      af[i] = *(const hfrag*)&As[(wm + i * 16 + l16) * ASTRIDE + quad * 8];
      wf[i] = *(const hfrag*)&Ws[wn + i * 16 + l16][quad * 8];
    }
    if constexpr (OUTM == 1) {
      // transposed: m = W-row (output dim), n = token
#pragma unroll
      for (int mi = 0; mi < 4; ++mi)
#pragma unroll
        for (int ni = 0; ni < 4; ++ni)
          acc[mi][ni] = MFMA16F(wf[mi], af[ni], acc[mi][ni], 0, 0, 0);
    } else {
#pragma unroll
      for (int mi = 0; mi < 4; ++mi)
#pragma unroll
        for (int ni = 0; ni < 4; ++ni)
          acc[mi][ni] = MFMA16F(af[mi], wf[ni], acc[mi][ni], 0, 0, 0);
    }
  }

  if constexpr (OUTM == 1) {
    // acc[mi][ni]: row = outputdim tile mi (quad*4+r), col = token tile ni (l16)
#pragma unroll
    for (int mi = 0; mi < 4; ++mi)
#pragma unroll
      for (int r = 0; r < 4; ++r) {
        int dim = bn + wn + mi * 16 + quad * 4 + r;
        float bv = bias[dim];
        int hh = dim >> 7, dh = dim & 127;
#pragma unroll
        for (int ni = 0; ni < 4; ++ni) {
          int tok = bm + wm + ni * 16 + l16;
          int b = tok >> 11, l = tok & 2047;
          ((u16*)outp)[(((size_t)(b * 16 + hh)) * 128 + dh) * 2048 + l] =
              f2h(acc[mi][ni][r] + bv);
        }
      }
  } else {
#pragma unroll
    for (int ni = 0; ni < 4; ++ni) {
      int n_g = bn + wn + ni * 16 + l16;
      float bv = bias[n_g];
#pragma unroll
      for (int mi = 0; mi < 4; ++mi)
#pragma unroll
        for (int r = 0; r < 4; ++r) {
          int m_g = bm + wm + mi * 16 + quad * 4 + r;
          ((float*)outp)[(size_t)m_g * 2048 + n_g] = acc[mi][ni][r] + bv;
        }
    }
  }
}

// ---------------------------------------------------------------------------
// Flash attention (causal). Q pre-scaled+pre-split fp16; K pre-split fp16;
// V^T fp16. K/V staged via global_load_lds into XOR-swizzled unpadded LDS.
// Softmax denominator via MFMA ones-column (V^T rows 128..143 = 1.0).
// ---------------------------------------------------------------------------
__global__ __launch_bounds__(256, 2)
void attn_k(const u16* __restrict__ qhi_g, const u16* __restrict__ qlo_g,
            const u16* __restrict__ khi_g, const u16* __restrict__ klo_g,
            const u16* __restrict__ vT, u16* __restrict__ Ow)
{
  __shared__ u16 Khi[64 * 128];   // swizzle: 16B-block ^= (row & 15)
  __shared__ u16 Klo[64 * 128];
  __shared__ u16 VT[144 * 64];    // rows 0..127 swizzled (^= row&7); 128..143 ones
  __shared__ u16 Pm[4][32][72];   // padded, per-wave C->A layout round trip

  const int tid = threadIdx.x, wave = tid >> 6, lane = tid & 63;
  const int quad = lane >> 4, l16 = lane & 15;
  const int qtile = blockIdx.x, bh = blockIdx.y;
  const u16* Qhb = qhi_g + (size_t)bh * 2048 * 128;
  const u16* Qlb = qlo_g + (size_t)bh * 2048 * 128;
  const u16* Khb = khi_g + (size_t)bh * 2048 * 128;
  const u16* Klb = klo_g + (size_t)bh * 2048 * 128;
  const u16* Vb  = vT    + (size_t)bh * 128 * 2048;
  const int qrow0 = qtile * 128 + wave * 32;

  // ones rows (dh 128..143) for the l-column MFMA; written once, swizzle-proof
  {
    int o = 128 * 64 + tid * 4;
    VT[o] = 0x3C00; VT[o + 1] = 0x3C00; VT[o + 2] = 0x3C00; VT[o + 3] = 0x3C00;
  }

  // Q fragments resident in registers (A-layout contiguous in global)
  hfrag qhf[2][4], qlf[2][4];
#pragma unroll
  for (int t = 0; t < 2; ++t)
#pragma unroll
    for (int f = 0; f < 4; ++f) {
      size_t off = (size_t)(qrow0 + t * 16 + l16) * 128 + f * 32 + quad * 8;
      qhf[t][f] = *(const hfrag*)(Qhb + off);
      qlf[t][f] = *(const hfrag*)(Qlb + off);
    }

  float mprev[2][4];
  f32x4 o[2][9] = {};                       // d=8 is the ones column (=l)
#pragma unroll
  for (int t = 0; t < 2; ++t)
#pragma unroll
    for (int r = 0; r < 4; ++r) mprev[t][r] = -3e38f;

  const int krl = lane >> 4, kpb = lane & 15;   // K staging: 4 rows x 16 blocks
  const int vrl = lane >> 3, vpb = lane & 7;    // V staging: 8 rows x 8 blocks

  const int nkv = 2 * (qtile + 1);
  for (int kt = 0; kt < nkv; ++kt) {
    const int kv0 = kt * 64;
    __syncthreads();                        // all waves done reading prev tile
#pragma unroll
    for (int i = 0; i < 4; ++i) {
      int r  = wave * 16 + i * 4 + krl;             // K local row 0..63
      int j  = kpb ^ (r & 15);                      // logical 16B block
      size_t kg = (size_t)(kv0 + r) * 128 + j * 8;
      gl2lds16(Khb + kg, &Khi[(wave * 16 + i * 4) * 128]);
      gl2lds16(Klb + kg, &Klo[(wave * 16 + i * 4) * 128]);
      int rv = wave * 32 + i * 8 + vrl;             // V^T row (dh) 0..127
      int jv = vpb ^ (rv & 7);
      gl2lds16(Vb + (size_t)rv * 2048 + kv0 + jv * 8,
               &VT[(wave * 32 + i * 8) * 64]);
    }
    __syncthreads();                        // vmcnt drained by barrier

    // S = Q K^T (fp16 3-prod: hh + lh + hl)
    f32x4 s[2][4] = {};
#pragma unroll
    for (int f = 0; f < 4; ++f)
#pragma unroll
      for (int c = 0; c < 4; ++c) {
        int poff = (c * 16 + l16) * 128 + (((f * 4 + quad) ^ l16) << 3);
        hfrag kf = *(const hfrag*)&Khi[poff];
        hfrag kl = *(const hfrag*)&Klo[poff];
#pragma unroll
        for (int t = 0; t < 2; ++t) {
          s[t][c] = MFMA16F(qhf[t][f], kf, s[t][c], 0, 0, 0);
          s[t][c] = MFMA16F(qlf[t][f], kf, s[t][c], 0, 0, 0);
          s[t][c] = MFMA16F(qhf[t][f], kl, s[t][c], 0, 0, 0);
        }
      }

    // online softmax (max only; sum comes from the ones-column MFMA)
#pragma unroll
    for (int t = 0; t < 2; ++t)
#pragma unroll
      for (int r = 0; r < 4; ++r) {
        const int rg = qrow0 + t * 16 + quad * 4 + r;
        float sv[4];
#pragma unroll
        for (int c = 0; c < 4; ++c) {
          int cg = kv0 + c * 16 + l16;
          sv[c] = (cg <= rg) ? s[t][c][r] : -1e7f;
        }
        float mx = fmaxf(fmaxf(sv[0], sv[1]), fmaxf(sv[2], sv[3]));
#pragma unroll
        for (int off = 1; off < 16; off <<= 1) mx = fmaxf(mx, __shfl_xor(mx, off));
        float mnew = fmaxf(mprev[t][r], mx);
        float al = __expf(mprev[t][r] - mnew);
        mprev[t][r] = mnew;
#pragma unroll
        for (int c = 0; c < 4; ++c) sv[c] = __expf(sv[c] - mnew);
#pragma unroll
        for (int d = 0; d < 9; ++d) o[t][d][r] *= al;
#pragma unroll
        for (int c = 0; c < 4; ++c)
          Pm[wave][t * 16 + quad * 4 + r][c * 16 + l16] = f2h(sv[c]);
      }
    // no barrier: Pm is per-wave, DS pipe in-order within a wave

    // O += P @ V  (d=8 accumulates the softmax denominator)
#pragma unroll
    for (int k2 = 0; k2 < 2; ++k2) {
      hfrag pf0 = *(const hfrag*)&Pm[wave][l16][k2 * 32 + quad * 8];
      hfrag pf1 = *(const hfrag*)&Pm[wave][16 + l16][k2 * 32 + quad * 8];
#pragma unroll
      for (int d = 0; d < 9; ++d) {
        hfrag vf = *(const hfrag*)
            &VT[(d * 16 + l16) * 64 + (((k2 * 4 + quad) ^ (l16 & 7)) << 3)];
        o[0][d] = MFMA16F(pf0, vf, o[0][d], 0, 0, 0);
        o[1][d] = MFMA16F(pf1, vf, o[1][d], 0, 0, 0);
      }
    }
  }

  // epilogue: normalize by ones-column, store fp16 to Ow[B,L,D]
  const int b = bh >> 4, h = bh & 15;
#pragma unroll
  for (int t = 0; t < 2; ++t)
#pragma unroll
    for (int r = 0; r < 4; ++r) {
      int rg = qrow0 + t * 16 + quad * 4 + r;
      float inv = 1.f / o[t][8][r];
#pragma unroll
      for (int d = 0; d < 8; ++d)
        Ow[((size_t)(b * 2048 + rg)) * 2048 + h * 128 + d * 16 + l16] =
            f2h(o[t][d][r] * inv);
    }
}

// ---------------------------------------------------------------------------
extern "C" void kernel_launch(void* const* d_in, const int* in_sizes, int n_in,
                              void* d_out, int out_size, void* d_ws, size_t ws_size,
                              hipStream_t stream) {
  const float* q  = (const float*)d_in[0];
  const float* k  = (const float*)d_in[1];
  const float* v  = (const float*)d_in[2];
  const float* Wq = (const float*)d_in[3];
  const float* bq = (const float*)d_in[4];
  const float* Wk = (const float*)d_in[5];
  const float* bk = (const float*)d_in[6];
  const float* Wv = (const float*)d_in[7];
  const float* bv = (const float*)d_in[8];
  const float* Wo = (const float*)d_in[9];
  const float* bo = (const float*)d_in[10];

  // Workspace (u16 units), 100.66 MB total (= round-2 proven budget):
  //   qHi qLo kHi kLo : 4 x 16.78 MB persistent fp16 planes
  //   X (16.78 MB)    : WqH|WqL, then WkH|WkL, then vT (sequential reuse)
  //   Ow (16.78 MB)
  u16* ws  = (u16*)d_ws;
  u16* qHi = ws;
  u16* qLo = ws + 8388608u;
  u16* kHi = ws + 16777216u;
  u16* kLo = ws + 25165824u;
  u16* WH  = ws + 33554432u;
  u16* WL  = ws + 37748736u;
  u16* vTb = ws + 33554432u;      // aliases WH/WL after gemm_qk's done
  u16* Owb = ws + 41943040u;

  dim3 blk(256);
  dim3 gg(16, 32);   // N/128, M/128
  presplit_h<<<4096, blk, 0, stream>>>(Wq, WH, WL);
  gemm_qk<0><<<gg, blk, 0, stream>>>(q, WH, WL, bq, qHi, qLo);
  presplit_h<<<4096, blk, 0, stream>>>(Wk, WH, WL);
  gemm_qk<1><<<gg, blk, 0, stream>>>(k, WH, WL, bk, kHi, kLo);
  gemm_pl<0, 1><<<gg, blk, 0, stream>>>(v, Wv, bv, vTb);
  attn_k<<<dim3(16, 32), blk, 0, stream>>>(qHi, qLo, kHi, kLo, vTb, Owb);
  gemm_pl<1, 2><<<gg, blk, 0, stream>>>(Owb, Wo, bo, d_out);
}

// Round 4
// 704.645 us; speedup vs baseline: 1.6704x; 1.0466x over previous
//
#include <hip/hip_runtime.h>

// Problem: B=2, L=2048, D=2048, H=16, DH=128, M=B*L=4096
typedef unsigned short u16;
typedef _Float16 hfrag __attribute__((ext_vector_type(8)));  // 8 fp16 = 4 VGPRs
typedef float f32x4 __attribute__((ext_vector_type(4)));     // MFMA C/D frag

#define MFMA16F __builtin_amdgcn_mfma_f32_16x16x32_f16

__device__ __forceinline__ u16 f2h(float f) {
  return __builtin_bit_cast(u16, (_Float16)f);
}
__device__ __forceinline__ void splith(float x, u16 &h, u16 &l) {
  _Float16 hh = (_Float16)x;                 // RNE
  _Float16 ll = (_Float16)(x - (float)hh);   // residual, ~2^-11 rel
  h = __builtin_bit_cast(u16, hh);
  l = __builtin_bit_cast(u16, ll);
}

// async global->LDS, 16B per lane. LDS dest = wave-uniform base + lane*16.
__device__ __forceinline__ void gl2lds16(const void* g, void* l) {
  __builtin_amdgcn_global_load_lds(
      (const __attribute__((address_space(1))) unsigned int*)g,
      (__attribute__((address_space(3))) unsigned int*)l, 16, 0, 0);
}

// ---------------------------------------------------------------------------
// Pre-split fp32 matrix -> fp16 hi/lo planes (one float4 per thread).
// ---------------------------------------------------------------------------
__global__ void presplit_h(const float* __restrict__ W, u16* __restrict__ hi,
                           u16* __restrict__ lo)
{
  size_t i = ((size_t)blockIdx.x * 256 + threadIdx.x) * 4;
  float4 x = *(const float4*)(W + i);
  ushort4 h, l;
  splith(x.x, h.x, l.x); splith(x.y, h.y, l.y);
  splith(x.z, h.z, l.z); splith(x.w, h.w, l.w);
  *(ushort4*)(hi + i) = h;
  *(ushort4*)(lo + i) = l;
}

// ---------------------------------------------------------------------------
// Split GEMM (Q/K proj): C[4096][2048] = A @ W^T + bias, 3-product fp16 hi/lo.
// A fp32 (split in-kernel, padded LDS); W pre-split fp16, global_load_lds
// into unpadded LDS (m97 pattern). EMIT 0: scale by sqrt(128) (Q). Output:
// fp16 hi/lo planes [B,H,L,DH].
// ---------------------------------------------------------------------------
template<int EMIT>
__global__ __launch_bounds__(256, 2)
void gemm_qk(const float* __restrict__ A, const u16* __restrict__ Wh_g,
             const u16* __restrict__ Wl_g, const float* __restrict__ bias,
             u16* __restrict__ ohi, u16* __restrict__ olo)
{
  __shared__ u16 Ahi[128][40];    // padded (80B rows, 16B-aligned)
  __shared__ u16 Alo[128][40];
  __shared__ u16 Whs[128 * 32];   // unpadded (global_load_lds dest)
  __shared__ u16 Wls[128 * 32];

  const int tid = threadIdx.x, wave = tid >> 6, lane = tid & 63;
  const int quad = lane >> 4, l16 = lane & 15;
  const int bm = blockIdx.y * 128, bn = blockIdx.x * 128;
  const int wm = (wave >> 1) * 64, wn = (wave & 1) * 64;
  const int rl = lane >> 2, cb = lane & 3;   // W staging: 16 rows x 4 blocks

  f32x4 acc[4][4] = {};

  for (int k0 = 0; k0 < 2048; k0 += 32) {
    __syncthreads();
    // async W hi/lo (8KB each): 2 issues/wave/plane
#pragma unroll
    for (int i = 0; i < 2; ++i) {
      int r0 = wave * 32 + i * 16;
      size_t goff = (size_t)(bn + r0 + rl) * 2048 + k0 + cb * 8;
      gl2lds16(Wh_g + goff, &Whs[r0 * 32]);
      gl2lds16(Wl_g + goff, &Wls[r0 * 32]);
    }
    // A: 128x32 fp32 -> fp16 hi/lo (VGPR path, overlaps the async loads)
#pragma unroll
    for (int it = 0; it < 4; ++it) {
      int idx = tid + it * 256;
      int row = idx >> 3, c4 = (idx & 7) << 2;
      float4 av = *(const float4*)(A + (size_t)(bm + row) * 2048 + k0 + c4);
      ushort4 h, l;
      splith(av.x, h.x, l.x); splith(av.y, h.y, l.y);
      splith(av.z, h.z, l.z); splith(av.w, h.w, l.w);
      *(ushort4*)&Ahi[row][c4] = h;
      *(ushort4*)&Alo[row][c4] = l;
    }
    __syncthreads();

    hfrag ah[4], al_[4], wh[4], wl[4];
#pragma unroll
    for (int i = 0; i < 4; ++i) {
      ah[i]  = *(const hfrag*)&Ahi[wm + i * 16 + l16][quad * 8];
      al_[i] = *(const hfrag*)&Alo[wm + i * 16 + l16][quad * 8];
      wh[i]  = *(const hfrag*)&Whs[(wn + i * 16 + l16) * 32 + quad * 8];
      wl[i]  = *(const hfrag*)&Wls[(wn + i * 16 + l16) * 32 + quad * 8];
    }
#pragma unroll
    for (int mi = 0; mi < 4; ++mi)
#pragma unroll
      for (int ni = 0; ni < 4; ++ni) {
        acc[mi][ni] = MFMA16F(ah[mi],  wh[ni], acc[mi][ni], 0, 0, 0);
        acc[mi][ni] = MFMA16F(al_[mi], wh[ni], acc[mi][ni], 0, 0, 0);
        acc[mi][ni] = MFMA16F(ah[mi],  wl[ni], acc[mi][ni], 0, 0, 0);
      }
  }

  const float SCALE = 11.31370849898476f;   // sqrt(128) — faithful source bug
#pragma unroll
  for (int ni = 0; ni < 4; ++ni) {
    int n_g = bn + wn + ni * 16 + l16;
    float bv = bias[n_g];
#pragma unroll
    for (int mi = 0; mi < 4; ++mi)
#pragma unroll
      for (int r = 0; r < 4; ++r) {
        int m_g = bm + wm + mi * 16 + quad * 4 + r;
        float v = acc[mi][ni][r] + bv;
        if constexpr (EMIT == 0) v *= SCALE;
        u16 h, l; splith(v, h, l);
        int b = m_g >> 11, ll = m_g & 2047, hh = n_g >> 7, dh = n_g & 127;
        size_t off = (((size_t)(b * 16 + hh)) * 2048 + ll) * 128 + dh;
        ohi[off] = h; olo[off] = l;
      }
  }
}

// ---------------------------------------------------------------------------
// Plain fp16 GEMM.
// AMODE 0: A fp32 (cvt in-kernel, padded LDS). AMODE 1: A fp16 global, staged
//          via global_load_lds (unpadded).  W always fp32, cvt in-kernel.
// OUTM 1: V-proj -> fp16 [B,H,DH,L]; computed TRANSPOSED (W rows as MFMA
//         A-operand) so stores are 32B-contiguous.  OUTM 2: fp32 [M][N].
// ---------------------------------------------------------------------------
template<int AMODE, int OUTM>
__global__ __launch_bounds__(256, 2)
void gemm_pl(const void* __restrict__ Ap, const float* __restrict__ W,
             const float* __restrict__ bias, void* __restrict__ outp)
{
  __shared__ u16 As[128 * 40];    // padded when AMODE0; stride 32 when AMODE1
  __shared__ u16 Ws[128][40];

  const int tid = threadIdx.x, wave = tid >> 6, lane = tid & 63;
  const int quad = lane >> 4, l16 = lane & 15;
  const int bm = blockIdx.y * 128, bn = blockIdx.x * 128;
  const int wm = (wave >> 1) * 64, wn = (wave & 1) * 64;
  const int rl = lane >> 2, cb = lane & 3;
  constexpr int ASTRIDE = (AMODE == 1) ? 32 : 40;

  f32x4 acc[4][4] = {};

  for (int k0 = 0; k0 < 2048; k0 += 32) {
    __syncthreads();
    if constexpr (AMODE == 1) {
      const u16* Ah = (const u16*)Ap;
#pragma unroll
      for (int i = 0; i < 2; ++i) {
        int r0 = wave * 32 + i * 16;
        gl2lds16(Ah + (size_t)(bm + r0 + rl) * 2048 + k0 + cb * 8,
                 &As[r0 * 32]);
      }
    }
#pragma unroll
    for (int it = 0; it < 4; ++it) {
      int idx = tid + it * 256;
      int row = idx >> 3, c4 = (idx & 7) << 2;
      float4 wv = *(const float4*)(W + (size_t)(bn + row) * 2048 + k0 + c4);
      ushort4 h;
      h.x = f2h(wv.x); h.y = f2h(wv.y); h.z = f2h(wv.z); h.w = f2h(wv.w);
      *(ushort4*)&Ws[row][c4] = h;
      if constexpr (AMODE == 0) {
        const float* A = (const float*)Ap;
        float4 av = *(const float4*)(A + (size_t)(bm + row) * 2048 + k0 + c4);
        ushort4 ha;
        ha.x = f2h(av.x); ha.y = f2h(av.y); ha.z = f2h(av.z); ha.w = f2h(av.w);
        *(ushort4*)&As[row * 40 + c4] = ha;
      }
    }
    __syncthreads();

    hfrag af[4], wf[4];
#pragma unroll
    for (int i = 0; i < 4; ++i) {
      af[i] = *(const hfrag*)&As[(wm + i * 16 + l16) * ASTRIDE + quad * 8];
      wf[i] = *(const hfrag*)&Ws[wn + i * 16 + l16][quad * 8];
    }
    if constexpr (OUTM == 1) {
      // transposed: m = W-row (output dim), n = token
#pragma unroll
      for (int mi = 0; mi < 4; ++mi)
#pragma unroll
        for (int ni = 0; ni < 4; ++ni)
          acc[mi][ni] = MFMA16F(wf[mi], af[ni], acc[mi][ni], 0, 0, 0);
    } else {
#pragma unroll
      for (int mi = 0; mi < 4; ++mi)
#pragma unroll
        for (int ni = 0; ni < 4; ++ni)
          acc[mi][ni] = MFMA16F(af[mi], wf[ni], acc[mi][ni], 0, 0, 0);
    }
  }

  if constexpr (OUTM == 1) {
#pragma unroll
    for (int mi = 0; mi < 4; ++mi)
#pragma unroll
      for (int r = 0; r < 4; ++r) {
        int dim = bn + wn + mi * 16 + quad * 4 + r;
        float bv = bias[dim];
        int hh = dim >> 7, dh = dim & 127;
#pragma unroll
        for (int ni = 0; ni < 4; ++ni) {
          int tok = bm + wm + ni * 16 + l16;
          int b = tok >> 11, l = tok & 2047;
          ((u16*)outp)[(((size_t)(b * 16 + hh)) * 128 + dh) * 2048 + l] =
              f2h(acc[mi][ni][r] + bv);
        }
      }
  } else {
#pragma unroll
    for (int ni = 0; ni < 4; ++ni) {
      int n_g = bn + wn + ni * 16 + l16;
      float bv = bias[n_g];
#pragma unroll
      for (int mi = 0; mi < 4; ++mi)
#pragma unroll
        for (int r = 0; r < 4; ++r) {
          int m_g = bm + wm + mi * 16 + quad * 4 + r;
          ((float*)outp)[(size_t)m_g * 2048 + n_g] = acc[mi][ni][r] + bv;
        }
    }
  }
}

// ---------------------------------------------------------------------------
// Flash attention (causal), balanced + double-buffered.
// Block x = 0..7 handles Q-tiles {x, 15-x}: every block = 34 KV iterations.
// Computes S^T = K Q^T (K as MFMA A-operand) so softmax rows sit in the lane
// dim: 2-shuffle row-max, P^T written as 8 ds_write_b64 (A-layout for PV).
// K/V staged via global_load_lds into XOR-swizzled dbuf LDS; loads for tile
// t+1 issue right after the barrier and drain at the next barrier (a full
// iteration in flight). Softmax denom via ones-column MFMA.
// ---------------------------------------------------------------------------
__global__ __launch_bounds__(256, 1)
void attn_k(const u16* __restrict__ qhi_g, const u16* __restrict__ qlo_g,
            const u16* __restrict__ khi_g, const u16* __restrict__ klo_g,
            const u16* __restrict__ vT, u16* __restrict__ Ow)
{
  __shared__ u16 KhiB[2][64 * 128];  // swizzle: 16B-block ^= (row & 15)
  __shared__ u16 KloB[2][64 * 128];
  __shared__ u16 VTB[2][128 * 64];   // swizzle: 16B-block ^= (row & 7)
  __shared__ u16 Vones[16 * 64];     // fp16 1.0 rows for the denom column
  __shared__ u16 PmA[4][32][72];     // per-wave P (A-layout), +8 pad

  const int tid = threadIdx.x, wave = tid >> 6, lane = tid & 63;
  const int quad = lane >> 4, l16 = lane & 15;
  const int bh = blockIdx.y;
  const u16* Qhb = qhi_g + (size_t)bh * 2048 * 128;
  const u16* Qlb = qlo_g + (size_t)bh * 2048 * 128;
  const u16* Khb = khi_g + (size_t)bh * 2048 * 128;
  const u16* Klb = klo_g + (size_t)bh * 2048 * 128;
  const u16* Vb  = vT    + (size_t)bh * 128 * 2048;

  const int krl = lane >> 4, kpb = lane & 15;   // K staging: 4 rows x 16 blocks
  const int vrl = lane >> 3, vpb = lane & 7;    // V staging: 8 rows x 8 blocks

  // ones block (written once; covered by the first barrier)
  {
    int o0 = tid * 4;
    Vones[o0] = 0x3C00; Vones[o0 + 1] = 0x3C00;
    Vones[o0 + 2] = 0x3C00; Vones[o0 + 3] = 0x3C00;
  }

  auto stage = [&](int kv0, int bsel) {
#pragma unroll
    for (int i = 0; i < 4; ++i) {
      int r = wave * 16 + i * 4 + krl;
      int j = kpb ^ (r & 15);
      size_t kg = (size_t)(kv0 + r) * 128 + j * 8;
      gl2lds16(Khb + kg, &KhiB[bsel][(wave * 16 + i * 4) * 128]);
      gl2lds16(Klb + kg, &KloB[bsel][(wave * 16 + i * 4) * 128]);
      int rv = wave * 32 + i * 8 + vrl;
      int jv = vpb ^ (rv & 7);
      gl2lds16(Vb + (size_t)rv * 2048 + kv0 + jv * 8,
               &VTB[bsel][(wave * 32 + i * 8) * 64]);
    }
  };

  const int b = bh >> 4, h = bh & 15;

#pragma unroll 1
  for (int ph = 0; ph < 2; ++ph) {
    const int qt = (ph == 0) ? (int)blockIdx.x : 15 - (int)blockIdx.x;
    const int qrow0 = qt * 128 + wave * 32;
    const int nkv = 2 * (qt + 1);   // always even -> last tile uses buf 1

    stage(0, 0);                    // buf0 free: prev phase ended on buf1

    // Q fragments (B-operand layout == contiguous rows), resident
    hfrag qhf[2][4], qlf[2][4];
#pragma unroll
    for (int t = 0; t < 2; ++t)
#pragma unroll
      for (int f = 0; f < 4; ++f) {
        size_t off = (size_t)(qrow0 + t * 16 + l16) * 128 + f * 32 + quad * 8;
        qhf[t][f] = *(const hfrag*)(Qhb + off);
        qlf[t][f] = *(const hfrag*)(Qlb + off);
      }

    float mprev[2] = {-3e38f, -3e38f};
    f32x4 o[2][9] = {};             // d=8: ones column (softmax denom)

#pragma unroll 1
    for (int kt = 0; kt < nkv; ++kt) {
      const int kv0 = kt * 64, bsel = kt & 1;
      __syncthreads();                          // drains tile-kt loads
      if (kt + 1 < nkv) stage((kt + 1) * 64, 1 - bsel);  // a full iter in flight

      if (kv0 <= qrow0 + 31) {                  // wave-uniform: any unmasked row?
        // S^T = K Q^T  (3-product fp16 split: hh + lh + hl)
        f32x4 st[4][2] = {};
#pragma unroll
        for (int f = 0; f < 4; ++f)
#pragma unroll
          for (int c = 0; c < 4; ++c) {
            int poff = (c * 16 + l16) * 128 + (((f * 4 + quad) ^ l16) << 3);
            hfrag kf = *(const hfrag*)&KhiB[bsel][poff];
            hfrag kl = *(const hfrag*)&KloB[bsel][poff];
#pragma unroll
            for (int t = 0; t < 2; ++t) {
              st[c][t] = MFMA16F(kf, qhf[t][f], st[c][t], 0, 0, 0);
              st[c][t] = MFMA16F(kf, qlf[t][f], st[c][t], 0, 0, 0);
              st[c][t] = MFMA16F(kl, qhf[t][f], st[c][t], 0, 0, 0);
            }
          }

        // softmax: row = t*16+l16 (lane dim), kv = c*16+quad*4+r
        const bool needmask = (kv0 + 64 > qrow0);
        float al2[2];
#pragma unroll
        for (int t = 0; t < 2; ++t) {
          const int rg = qrow0 + t * 16 + l16;
          if (needmask) {
#pragma unroll
            for (int c = 0; c < 4; ++c)
#pragma unroll
              for (int r = 0; r < 4; ++r)
                if (kv0 + c * 16 + quad * 4 + r > rg) st[c][t][r] = -1e7f;
          }
          float mx = st[0][t][0];
#pragma unroll
          for (int c = 0; c < 4; ++c)
#pragma unroll
            for (int r = 0; r < 4; ++r) mx = fmaxf(mx, st[c][t][r]);
          mx = fmaxf(mx, __shfl_xor(mx, 16));
          mx = fmaxf(mx, __shfl_xor(mx, 32));
          float mnew = fmaxf(mprev[t], mx);
          al2[t] = __expf(mprev[t] - mnew);
          mprev[t] = mnew;
#pragma unroll
          for (int c = 0; c < 4; ++c) {
            ushort4 pk;
            pk.x = f2h(__expf(st[c][t][0] - mnew));
            pk.y = f2h(__expf(st[c][t][1] - mnew));
            pk.z = f2h(__expf(st[c][t][2] - mnew));
            pk.w = f2h(__expf(st[c][t][3] - mnew));
            *(ushort4*)&PmA[wave][t * 16 + l16][c * 16 + quad * 4] = pk;
          }
        }
        // rescale O only when some row's max moved (wave-uniform gate)
        if (__ballot(al2[0] != 1.f || al2[1] != 1.f)) {
#pragma unroll
          for (int t = 0; t < 2; ++t) {
            f32x4 av;
            av[0] = __shfl(al2[t], quad * 4 + 0);
            av[1] = __shfl(al2[t], quad * 4 + 1);
            av[2] = __shfl(al2[t], quad * 4 + 2);
            av[3] = __shfl(al2[t], quad * 4 + 3);
#pragma unroll
            for (int d = 0; d < 9; ++d) o[t][d] *= av;
          }
        }

        // O += P V   (P from per-wave LDS in A-layout; d=8 accumulates denom)
#pragma unroll
        for (int k2 = 0; k2 < 2; ++k2) {
          hfrag pf0 = *(const hfrag*)&PmA[wave][l16][k2 * 32 + quad * 8];
          hfrag pf1 = *(const hfrag*)&PmA[wave][16 + l16][k2 * 32 + quad * 8];
#pragma unroll
          for (int d = 0; d < 9; ++d) {
            const u16* vp = (d < 8)
                ? &VTB[bsel][(d * 16 + l16) * 64 + (((k2 * 4 + quad) ^ (l16 & 7)) << 3)]
                : &Vones[l16 * 64 + ((k2 * 4 + quad) << 3)];
            hfrag vf = *(const hfrag*)vp;
            o[0][d] = MFMA16F(pf0, vf, o[0][d], 0, 0, 0);
            o[1][d] = MFMA16F(pf1, vf, o[1][d], 0, 0, 0);
          }
        }
      }
    }

    // epilogue: normalize by the ones column, store fp16 to Ow[B,L,D]
#pragma unroll
    for (int t = 0; t < 2; ++t)
#pragma unroll
      for (int r = 0; r < 4; ++r) {
        int rg = qrow0 + t * 16 + quad * 4 + r;
        float inv = 1.f / o[t][8][r];
#pragma unroll
        for (int d = 0; d < 8; ++d)
          Ow[((size_t)(b * 2048 + rg)) * 2048 + h * 128 + d * 16 + l16] =
              f2h(o[t][d][r] * inv);
      }
  }
}

// ---------------------------------------------------------------------------
extern "C" void kernel_launch(void* const* d_in, const int* in_sizes, int n_in,
                              void* d_out, int out_size, void* d_ws, size_t ws_size,
                              hipStream_t stream) {
  const float* q  = (const float*)d_in[0];
  const float* k  = (const float*)d_in[1];
  const float* v  = (const float*)d_in[2];
  const float* Wq = (const float*)d_in[3];
  const float* bq = (const float*)d_in[4];
  const float* Wk = (const float*)d_in[5];
  const float* bk = (const float*)d_in[6];
  const float* Wv = (const float*)d_in[7];
  const float* bv = (const float*)d_in[8];
  const float* Wo = (const float*)d_in[9];
  const float* bo = (const float*)d_in[10];

  // Workspace (u16 units), 100.66 MB (proven budget):
  //   qHi qLo kHi kLo : 4 x 16.78 MB persistent fp16 planes
  //   X (16.78 MB)    : WqH|WqL -> WkH|WkL -> vT (sequential reuse)
  //   Ow (16.78 MB)
  u16* ws  = (u16*)d_ws;
  u16* qHi = ws;
  u16* qLo = ws + 8388608u;
  u16* kHi = ws + 16777216u;
  u16* kLo = ws + 25165824u;
  u16* WH  = ws + 33554432u;
  u16* WL  = ws + 37748736u;
  u16* vTb = ws + 33554432u;      // aliases WH/WL after gemm_qk's done
  u16* Owb = ws + 41943040u;

  dim3 blk(256);
  dim3 gg(16, 32);   // N/128, M/128
  presplit_h<<<4096, blk, 0, stream>>>(Wq, WH, WL);
  gemm_qk<0><<<gg, blk, 0, stream>>>(q, WH, WL, bq, qHi, qLo);
  presplit_h<<<4096, blk, 0, stream>>>(Wk, WH, WL);
  gemm_qk<1><<<gg, blk, 0, stream>>>(k, WH, WL, bk, kHi, kLo);
  gemm_pl<0, 1><<<gg, blk, 0, stream>>>(v, Wv, bv, vTb);
  attn_k<<<dim3(8, 32), blk, 0, stream>>>(qHi, qLo, kHi, kLo, vTb, Owb);
  gemm_pl<1, 2><<<gg, blk, 0, stream>>>(Owb, Wo, bo, d_out);
}

// Round 5
// 637.464 us; speedup vs baseline: 1.8465x; 1.1054x over previous
//
#include <hip/hip_runtime.h>

// Problem: B=2, L=2048, D=2048, H=16, DH=128, M=B*L=4096
typedef unsigned short u16;
typedef _Float16 hfrag __attribute__((ext_vector_type(8)));  // 8 fp16 = 4 VGPRs
typedef float f32x4 __attribute__((ext_vector_type(4)));     // MFMA C/D frag

#define MFMA16F __builtin_amdgcn_mfma_f32_16x16x32_f16

__device__ __forceinline__ u16 f2h(float f) {
  return __builtin_bit_cast(u16, (_Float16)f);
}
__device__ __forceinline__ void splith(float x, u16 &h, u16 &l) {
  _Float16 hh = (_Float16)x;                 // RNE
  _Float16 ll = (_Float16)(x - (float)hh);   // residual, ~2^-11 rel
  h = __builtin_bit_cast(u16, hh);
  l = __builtin_bit_cast(u16, ll);
}

// async global->LDS, 16B per lane. LDS dest = wave-uniform base + lane*16.
__device__ __forceinline__ void gl2lds16(const void* g, void* l) {
  __builtin_amdgcn_global_load_lds(
      (const __attribute__((address_space(1))) unsigned int*)g,
      (__attribute__((address_space(3))) unsigned int*)l, 16, 0, 0);
}

// ---------------------------------------------------------------------------
// fp32 -> fp16 (hi plane only; residual product dropped per error budget).
// ---------------------------------------------------------------------------
__global__ void precvt_h(const float* __restrict__ W, u16* __restrict__ hi)
{
  size_t i = ((size_t)blockIdx.x * 256 + threadIdx.x) * 4;
  float4 x = *(const float4*)(W + i);
  ushort4 h;
  h.x = f2h(x.x); h.y = f2h(x.y); h.z = f2h(x.z); h.w = f2h(x.w);
  *(ushort4*)(hi + i) = h;
}

// ---------------------------------------------------------------------------
// Split GEMM (Q/K proj): C[4096][2048] = A @ W^T + bias, 2-product fp16
// (ah*wh + al*wh; W residual dropped — adds ~0.018 to score vs sigma 105).
// A fp32 (split in-kernel, padded LDS); W fp16 via global_load_lds.
// EMIT 0: scale by sqrt(128), emit hi+lo planes (Q).
// EMIT 1: emit hi plane only (K — its residual is never consumed).
// ---------------------------------------------------------------------------
template<int EMIT>
__global__ __launch_bounds__(256, 2)
void gemm_qk(const float* __restrict__ A, const u16* __restrict__ Wh_g,
             const float* __restrict__ bias,
             u16* __restrict__ ohi, u16* __restrict__ olo)
{
  __shared__ u16 Ahi[128][40];    // padded (80B rows, 16B-aligned)
  __shared__ u16 Alo[128][40];
  __shared__ u16 Whs[128 * 32];   // unpadded (global_load_lds dest)

  const int tid = threadIdx.x, wave = tid >> 6, lane = tid & 63;
  const int quad = lane >> 4, l16 = lane & 15;
  const int bm = blockIdx.y * 128, bn = blockIdx.x * 128;
  const int wm = (wave >> 1) * 64, wn = (wave & 1) * 64;
  const int rl = lane >> 2, cb = lane & 3;   // W staging: 16 rows x 4 blocks

  f32x4 acc[4][4] = {};

  for (int k0 = 0; k0 < 2048; k0 += 32) {
    __syncthreads();
    // async W (8KB): 2 issues/wave
#pragma unroll
    for (int i = 0; i < 2; ++i) {
      int r0 = wave * 32 + i * 16;
      gl2lds16(Wh_g + (size_t)(bn + r0 + rl) * 2048 + k0 + cb * 8,
               &Whs[r0 * 32]);
    }
    // A: 128x32 fp32 -> fp16 hi/lo (VGPR path, overlaps the async loads)
#pragma unroll
    for (int it = 0; it < 4; ++it) {
      int idx = tid + it * 256;
      int row = idx >> 3, c4 = (idx & 7) << 2;
      float4 av = *(const float4*)(A + (size_t)(bm + row) * 2048 + k0 + c4);
      ushort4 h, l;
      splith(av.x, h.x, l.x); splith(av.y, h.y, l.y);
      splith(av.z, h.z, l.z); splith(av.w, h.w, l.w);
      *(ushort4*)&Ahi[row][c4] = h;
      *(ushort4*)&Alo[row][c4] = l;
    }
    __syncthreads();

    hfrag ah[4], al_[4], wh[4];
#pragma unroll
    for (int i = 0; i < 4; ++i) {
      ah[i]  = *(const hfrag*)&Ahi[wm + i * 16 + l16][quad * 8];
      al_[i] = *(const hfrag*)&Alo[wm + i * 16 + l16][quad * 8];
      wh[i]  = *(const hfrag*)&Whs[(wn + i * 16 + l16) * 32 + quad * 8];
    }
#pragma unroll
    for (int mi = 0; mi < 4; ++mi)
#pragma unroll
      for (int ni = 0; ni < 4; ++ni) {
        acc[mi][ni] = MFMA16F(ah[mi],  wh[ni], acc[mi][ni], 0, 0, 0);
        acc[mi][ni] = MFMA16F(al_[mi], wh[ni], acc[mi][ni], 0, 0, 0);
      }
  }

  const float SCALE = 11.31370849898476f;   // sqrt(128) — faithful source bug
#pragma unroll
  for (int ni = 0; ni < 4; ++ni) {
    int n_g = bn + wn + ni * 16 + l16;
    float bv = bias[n_g];
#pragma unroll
    for (int mi = 0; mi < 4; ++mi)
#pragma unroll
      for (int r = 0; r < 4; ++r) {
        int m_g = bm + wm + mi * 16 + quad * 4 + r;
        float v = acc[mi][ni][r] + bv;
        int b = m_g >> 11, ll = m_g & 2047, hh = n_g >> 7, dh = n_g & 127;
        size_t off = (((size_t)(b * 16 + hh)) * 2048 + ll) * 128 + dh;
        if constexpr (EMIT == 0) {
          v *= SCALE;
          u16 h, l; splith(v, h, l);
          ohi[off] = h; olo[off] = l;
        } else {
          ohi[off] = f2h(v);
        }
      }
  }
}

// ---------------------------------------------------------------------------
// Plain fp16 GEMM.
// AMODE 0: A fp32 (cvt in-kernel, padded LDS). AMODE 1: A fp16 global, staged
//          via global_load_lds (unpadded).  W always fp32, cvt in-kernel.
// OUTM 1: V-proj -> fp16 [B,H,DH,L]; computed TRANSPOSED (W rows as MFMA
//         A-operand) so stores are 32B-contiguous.  OUTM 2: fp32 [M][N].
// ---------------------------------------------------------------------------
template<int AMODE, int OUTM>
__global__ __launch_bounds__(256, 2)
void gemm_pl(const void* __restrict__ Ap, const float* __restrict__ W,
             const float* __restrict__ bias, void* __restrict__ outp)
{
  __shared__ u16 As[128 * 40];    // padded when AMODE0; stride 32 when AMODE1
  __shared__ u16 Ws[128][40];

  const int tid = threadIdx.x, wave = tid >> 6, lane = tid & 63;
  const int quad = lane >> 4, l16 = lane & 15;
  const int bm = blockIdx.y * 128, bn = blockIdx.x * 128;
  const int wm = (wave >> 1) * 64, wn = (wave & 1) * 64;
  const int rl = lane >> 2, cb = lane & 3;
  constexpr int ASTRIDE = (AMODE == 1) ? 32 : 40;

  f32x4 acc[4][4] = {};

  for (int k0 = 0; k0 < 2048; k0 += 32) {
    __syncthreads();
    if constexpr (AMODE == 1) {
      const u16* Ah = (const u16*)Ap;
#pragma unroll
      for (int i = 0; i < 2; ++i) {
        int r0 = wave * 32 + i * 16;
        gl2lds16(Ah + (size_t)(bm + r0 + rl) * 2048 + k0 + cb * 8,
                 &As[r0 * 32]);
      }
    }
#pragma unroll
    for (int it = 0; it < 4; ++it) {
      int idx = tid + it * 256;
      int row = idx >> 3, c4 = (idx & 7) << 2;
      float4 wv = *(const float4*)(W + (size_t)(bn + row) * 2048 + k0 + c4);
      ushort4 h;
      h.x = f2h(wv.x); h.y = f2h(wv.y); h.z = f2h(wv.z); h.w = f2h(wv.w);
      *(ushort4*)&Ws[row][c4] = h;
      if constexpr (AMODE == 0) {
        const float* A = (const float*)Ap;
        float4 av = *(const float4*)(A + (size_t)(bm + row) * 2048 + k0 + c4);
        ushort4 ha;
        ha.x = f2h(av.x); ha.y = f2h(av.y); ha.z = f2h(av.z); ha.w = f2h(av.w);
        *(ushort4*)&As[row * 40 + c4] = ha;
      }
    }
    __syncthreads();

    hfrag af[4], wf[4];
#pragma unroll
    for (int i = 0; i < 4; ++i) {
      af[i] = *(const hfrag*)&As[(wm + i * 16 + l16) * ASTRIDE + quad * 8];
      wf[i] = *(const hfrag*)&Ws[wn + i * 16 + l16][quad * 8];
    }
    if constexpr (OUTM == 1) {
#pragma unroll
      for (int mi = 0; mi < 4; ++mi)
#pragma unroll
        for (int ni = 0; ni < 4; ++ni)
          acc[mi][ni] = MFMA16F(wf[mi], af[ni], acc[mi][ni], 0, 0, 0);
    } else {
#pragma unroll
      for (int mi = 0; mi < 4; ++mi)
#pragma unroll
        for (int ni = 0; ni < 4; ++ni)
          acc[mi][ni] = MFMA16F(af[mi], wf[ni], acc[mi][ni], 0, 0, 0);
    }
  }

  if constexpr (OUTM == 1) {
#pragma unroll
    for (int mi = 0; mi < 4; ++mi)
#pragma unroll
      for (int r = 0; r < 4; ++r) {
        int dim = bn + wn + mi * 16 + quad * 4 + r;
        float bv = bias[dim];
        int hh = dim >> 7, dh = dim & 127;
#pragma unroll
        for (int ni = 0; ni < 4; ++ni) {
          int tok = bm + wm + ni * 16 + l16;
          int b = tok >> 11, l = tok & 2047;
          ((u16*)outp)[(((size_t)(b * 16 + hh)) * 128 + dh) * 2048 + l] =
              f2h(acc[mi][ni][r] + bv);
        }
      }
  } else {
#pragma unroll
    for (int ni = 0; ni < 4; ++ni) {
      int n_g = bn + wn + ni * 16 + l16;
      float bv = bias[n_g];
#pragma unroll
      for (int mi = 0; mi < 4; ++mi)
#pragma unroll
        for (int r = 0; r < 4; ++r) {
          int m_g = bm + wm + mi * 16 + quad * 4 + r;
          ((float*)outp)[(size_t)m_g * 2048 + n_g] = acc[mi][ni][r] + bv;
        }
    }
  }
}

// ---------------------------------------------------------------------------
// Flash attention (causal), balanced + double-buffered + XCD-swizzled.
// 1-D grid of 256: bh = bid & 31, x = bid >> 5 -> all 8 x-blocks of a head
// share id mod 8 (same XCD) so K/V stream hits that XCD's L2.
// Block x handles Q-tiles {x, 15-x}: uniform 34 KV iterations.
// S^T = K Q^T, 2-product fp16 (K residual dropped: +0.025 on scores sigma
// 105). K/V staged via global_load_lds into XOR-swizzled dbuf LDS, one full
// iteration in flight. Softmax denom via ones-column MFMA (register frag).
// ---------------------------------------------------------------------------
__global__ __launch_bounds__(256, 1)
void attn_k(const u16* __restrict__ qhi_g, const u16* __restrict__ qlo_g,
            const u16* __restrict__ khi_g, const u16* __restrict__ vT,
            u16* __restrict__ Ow)
{
  __shared__ u16 KhiB[2][64 * 128];  // swizzle: 16B-block ^= (row & 15)
  __shared__ u16 VTB[2][128 * 64];   // swizzle: 16B-block ^= (row & 7)
  __shared__ u16 PmA[4][32][72];     // per-wave P (A-layout), +8 pad

  const int tid = threadIdx.x, wave = tid >> 6, lane = tid & 63;
  const int quad = lane >> 4, l16 = lane & 15;
  const int bh = blockIdx.x & 31, qx = blockIdx.x >> 5;
  const u16* Qhb = qhi_g + (size_t)bh * 2048 * 128;
  const u16* Qlb = qlo_g + (size_t)bh * 2048 * 128;
  const u16* Khb = khi_g + (size_t)bh * 2048 * 128;
  const u16* Vb  = vT    + (size_t)bh * 128 * 2048;

  const int krl = lane >> 4, kpb = lane & 15;   // K staging: 4 rows x 16 blocks
  const int vrl = lane >> 3, vpb = lane & 7;    // V staging: 8 rows x 8 blocks

  hfrag ones;
#pragma unroll
  for (int j = 0; j < 8; ++j) ones[j] = (_Float16)1.0f;

  auto stage = [&](int kv0, int bsel) {
#pragma unroll
    for (int i = 0; i < 4; ++i) {
      int r = wave * 16 + i * 4 + krl;
      int j = kpb ^ (r & 15);
      gl2lds16(Khb + (size_t)(kv0 + r) * 128 + j * 8,
               &KhiB[bsel][(wave * 16 + i * 4) * 128]);
      int rv = wave * 32 + i * 8 + vrl;
      int jv = vpb ^ (rv & 7);
      gl2lds16(Vb + (size_t)rv * 2048 + kv0 + jv * 8,
               &VTB[bsel][(wave * 32 + i * 8) * 64]);
    }
  };

  const int b = bh >> 4, h = bh & 15;

#pragma unroll 1
  for (int ph = 0; ph < 2; ++ph) {
    const int qt = (ph == 0) ? qx : 15 - qx;
    const int qrow0 = qt * 128 + wave * 32;
    const int nkv = 2 * (qt + 1);   // always even -> last tile uses buf 1

    stage(0, 0);                    // buf0 free: prev phase ended on buf1

    // Q fragments (B-operand layout == contiguous rows), resident
    hfrag qhf[2][4], qlf[2][4];
#pragma unroll
    for (int t = 0; t < 2; ++t)
#pragma unroll
      for (int f = 0; f < 4; ++f) {
        size_t off = (size_t)(qrow0 + t * 16 + l16) * 128 + f * 32 + quad * 8;
        qhf[t][f] = *(const hfrag*)(Qhb + off);
        qlf[t][f] = *(const hfrag*)(Qlb + off);
      }

    float mprev[2] = {-3e38f, -3e38f};
    f32x4 o[2][9] = {};             // d=8: ones column (softmax denom)

#pragma unroll 1
    for (int kt = 0; kt < nkv; ++kt) {
      const int kv0 = kt * 64, bsel = kt & 1;
      __syncthreads();                          // drains tile-kt loads
      if (kt + 1 < nkv) stage((kt + 1) * 64, 1 - bsel);  // a full iter in flight

      if (kv0 <= qrow0 + 31) {                  // wave-uniform: any unmasked row?
        // S^T = K Q^T  (2-product fp16: k*qh + k*ql)
        f32x4 st[4][2] = {};
#pragma unroll
        for (int f = 0; f < 4; ++f)
#pragma unroll
          for (int c = 0; c < 4; ++c) {
            int poff = (c * 16 + l16) * 128 + (((f * 4 + quad) ^ l16) << 3);
            hfrag kf = *(const hfrag*)&KhiB[bsel][poff];
#pragma unroll
            for (int t = 0; t < 2; ++t) {
              st[c][t] = MFMA16F(kf, qhf[t][f], st[c][t], 0, 0, 0);
              st[c][t] = MFMA16F(kf, qlf[t][f], st[c][t], 0, 0, 0);
            }
          }

        // softmax: row = t*16+l16 (lane dim), kv = c*16+quad*4+r
        const bool needmask = (kv0 + 64 > qrow0);
        float al2[2];
#pragma unroll
        for (int t = 0; t < 2; ++t) {
          const int rg = qrow0 + t * 16 + l16;
          if (needmask) {
#pragma unroll
            for (int c = 0; c < 4; ++c)
#pragma unroll
              for (int r = 0; r < 4; ++r)
                if (kv0 + c * 16 + quad * 4 + r > rg) st[c][t][r] = -1e7f;
          }
          float mx = st[0][t][0];
#pragma unroll
          for (int c = 0; c < 4; ++c)
#pragma unroll
            for (int r = 0; r < 4; ++r) mx = fmaxf(mx, st[c][t][r]);
          mx = fmaxf(mx, __shfl_xor(mx, 16));
          mx = fmaxf(mx, __shfl_xor(mx, 32));
          float mnew = fmaxf(mprev[t], mx);
          al2[t] = __expf(mprev[t] - mnew);
          mprev[t] = mnew;
#pragma unroll
          for (int c = 0; c < 4; ++c) {
            ushort4 pk;
            pk.x = f2h(__expf(st[c][t][0] - mnew));
            pk.y = f2h(__expf(st[c][t][1] - mnew));
            pk.z = f2h(__expf(st[c][t][2] - mnew));
            pk.w = f2h(__expf(st[c][t][3] - mnew));
            *(ushort4*)&PmA[wave][t * 16 + l16][c * 16 + quad * 4] = pk;
          }
        }
        // rescale O only when some row's max moved (wave-uniform gate)
        if (__ballot(al2[0] != 1.f || al2[1] != 1.f)) {
#pragma unroll
          for (int t = 0; t < 2; ++t) {
            f32x4 av;
            av[0] = __shfl(al2[t], quad * 4 + 0);
            av[1] = __shfl(al2[t], quad * 4 + 1);
            av[2] = __shfl(al2[t], quad * 4 + 2);
            av[3] = __shfl(al2[t], quad * 4 + 3);
#pragma unroll
            for (int d = 0; d < 9; ++d) o[t][d] *= av;
          }
        }

        // O += P V   (P from per-wave LDS in A-layout; d=8 accumulates denom)
#pragma unroll
        for (int k2 = 0; k2 < 2; ++k2) {
          hfrag pf0 = *(const hfrag*)&PmA[wave][l16][k2 * 32 + quad * 8];
          hfrag pf1 = *(const hfrag*)&PmA[wave][16 + l16][k2 * 32 + quad * 8];
#pragma unroll
          for (int d = 0; d < 9; ++d) {
            hfrag vf = (d < 8)
                ? *(const hfrag*)&VTB[bsel][(d * 16 + l16) * 64 +
                                            (((k2 * 4 + quad) ^ (l16 & 7)) << 3)]
                : ones;
            o[0][d] = MFMA16F(pf0, vf, o[0][d], 0, 0, 0);
            o[1][d] = MFMA16F(pf1, vf, o[1][d], 0, 0, 0);
          }
        }
      }
    }

    // epilogue: normalize by the ones column, store fp16 to Ow[B,L,D]
#pragma unroll
    for (int t = 0; t < 2; ++t)
#pragma unroll
      for (int r = 0; r < 4; ++r) {
        int rg = qrow0 + t * 16 + quad * 4 + r;
        float inv = 1.f / o[t][8][r];
#pragma unroll
        for (int d = 0; d < 8; ++d)
          Ow[((size_t)(b * 2048 + rg)) * 2048 + h * 128 + d * 16 + l16] =
              f2h(o[t][d][r] * inv);
      }
  }
}

// ---------------------------------------------------------------------------
extern "C" void kernel_launch(void* const* d_in, const int* in_sizes, int n_in,
                              void* d_out, int out_size, void* d_ws, size_t ws_size,
                              hipStream_t stream) {
  const float* q  = (const float*)d_in[0];
  const float* k  = (const float*)d_in[1];
  const float* v  = (const float*)d_in[2];
  const float* Wq = (const float*)d_in[3];
  const float* bq = (const float*)d_in[4];
  const float* Wk = (const float*)d_in[5];
  const float* bk = (const float*)d_in[6];
  const float* Wv = (const float*)d_in[7];
  const float* bv = (const float*)d_in[8];
  const float* Wo = (const float*)d_in[9];
  const float* bo = (const float*)d_in[10];

  // Workspace (u16 units), <=100.66 MB proven budget:
  //   qHi qLo kHi : 3 x 16.78 MB persistent fp16 planes
  //   X (8.39 MB) : WqH -> WkH -> (first half of vT region reuse)
  //   vT, Ow      : 16.78 MB each
  u16* ws  = (u16*)d_ws;
  u16* qHi = ws;
  u16* qLo = ws + 8388608u;
  u16* kHi = ws + 16777216u;
  u16* WH  = ws + 25165824u;      // 4.19M u16 = 8.39 MB
  u16* vTb = ws + 29360128u;
  u16* Owb = ws + 37748736u;

  dim3 blk(256);
  dim3 gg(16, 32);   // N/128, M/128
  precvt_h<<<4096, blk, 0, stream>>>(Wq, WH);
  gemm_qk<0><<<gg, blk, 0, stream>>>(q, WH, bq, qHi, qLo);
  precvt_h<<<4096, blk, 0, stream>>>(Wk, WH);
  gemm_qk<1><<<gg, blk, 0, stream>>>(k, WH, bk, kHi, nullptr);
  gemm_pl<0, 1><<<gg, blk, 0, stream>>>(v, Wv, bv, vTb);
  attn_k<<<dim3(256), blk, 0, stream>>>(qHi, qLo, kHi, vTb, Owb);
  gemm_pl<1, 2><<<gg, blk, 0, stream>>>(Owb, Wo, bo, d_out);
}